// Round 1
// baseline (341.803 us; speedup 1.0000x reference)
//
#include <hip/hip_runtime.h>
#include <hip/hip_bf16.h>
#include <hip/hip_fp16.h>

// ---------------------------------------------------------------------------
// EnhancedRGCN (3-layer GAT), N=100000 nodes, E=3200000 edges, D=32.
// CSR-by-dst via FIXED-CAPACITY bucket binning (bucket = dst>>7, 128 nodes,
// CAPB=6144 slots). R13: k_bin rewritten to LDS-staged, bucket-grouped RUN
// writeback — block-local counting scatter into a 32KB stage buffer, one-wave
// shfl scan over 1024 bins, EXACT-count reservations (no 32B rounding, no
// sentinels), per-bucket coalesced run copy (avg ~10.5 contiguous uints).
// Kills the ~16x write amplification of the old isolated-4B pair scatter and
// the 34% sentinel-pad inflation k_bucket_sort used to re-read. Cursors are
// bucket-RELATIVE now; k_initcur replaced by hipMemsetAsync.
// k_edge (R12, unchanged): TWO NODES PER WAVE (half-wave per node); pass B
// 2 slots x 8 entries = 16 edges/node/iter, 8 half2 gathers in flight,
// fma_mix accumulate; deferred 5-level denominator butterfly. No segment-max
// (shift-invariant softmax, bounded logits); no float atomics.
// ---------------------------------------------------------------------------

#define NPB  128    // nodes per bucket (dst>>7)
#define CAPB 6144   // slots per bucket (exact mean ~4092, >30 sigma room)
#define PAD_SENTINEL 0xFFFFFFFFu

// ---------------- pass 1: bin edges into fixed bucket regions --------------
// LDS-staged: histogram -> (scan || global reservations) -> LDS scatter ->
// per-bucket coalesced run writeback. bucket_cursor[b] is RELATIVE (starts 0).
__global__ void __launch_bounds__(1024)
k_bin(const int* __restrict__ src, const int* __restrict__ dst,
      int* __restrict__ bucket_cursor, unsigned int* __restrict__ pairs,
      int e, int nb) {
    __shared__ int h[1024];                 // per-bucket count (this block)
    __shared__ int bs[1024];                // block-local exclusive base
    __shared__ int cb[1024];                // global (relative) reservation
    __shared__ unsigned int stage[8192];    // bucket-grouped staged pairs
    int t = threadIdx.x;
    h[t] = 0;
    __syncthreads();
    int e4 = e >> 2;
    int base4 = blockIdx.x * 2048;          // 1024 threads x 2 int4 each
    int boff[8];                            // (bucket<<16) | rank, or -1
    unsigned int pk[8];
#pragma unroll
    for (int k = 0; k < 2; k++) {
        int i4 = base4 + k * 1024 + t;
        if (i4 < e4) {
            int4 dv = ((const int4*)dst)[i4];
            int4 sv = ((const int4*)src)[i4];
            const int* dd = (const int*)&dv;
            const int* ss = (const int*)&sv;
#pragma unroll
            for (int j = 0; j < 4; j++) {
                int q = 4 * k + j;
                int d = dd[j];
                int b = d >> 7;
                pk[q] = ((unsigned int)ss[j] << 7) | (unsigned int)(d & 127);
                int off = atomicAdd(&h[b], 1);
                boff[q] = (b << 16) | off;
            }
        } else {
#pragma unroll
            for (int j = 0; j < 4; j++) boff[4 * k + j] = -1;
        }
    }
    __syncthreads();
    // global reservations (threads 128..128+nb) overlap the scan (wave 0):
    // both only read h[]; atomic latency hides under the shfl scan.
    if (t >= 128 && t - 128 < nb) {
        int b = t - 128;
        int c = h[b];
        cb[b] = c ? atomicAdd(&bucket_cursor[b], c) : 0;
    }
    if (t < 64) {                           // wave 0: scan 1024 bins (16/lane)
        int sum = 0;
#pragma unroll
        for (int j = 0; j < 16; j++) sum += h[t * 16 + j];
        int run = sum;
#pragma unroll
        for (int off = 1; off < 64; off <<= 1) {
            int v = __shfl_up(run, off, 64);
            if (t >= off) run += v;
        }
        int base = run - sum;               // exclusive
#pragma unroll
        for (int j = 0; j < 16; j++) {
            int b = t * 16 + j;
            bs[b] = base;
            base += h[b];
        }
    }
    __syncthreads();
#pragma unroll
    for (int q = 0; q < 8; q++) {           // scatter into bucket-grouped LDS
        if (boff[q] >= 0) {
            int b = boff[q] >> 16;
            stage[bs[b] + (boff[q] & 0xFFFF)] = pk[q];
        }
    }
    __syncthreads();
    // coalesced run writeback: wave w handles buckets w, w+16, ...
    int wv = t >> 6, ln = t & 63;
    for (int b = wv; b < nb; b += 16) {
        int c = h[b];
        if (c == 0) continue;
        int gb = cb[b];
        int room = CAPB - gb;               // overflow guard (relative cursor)
        if (c > room) c = (room > 0) ? room : 0;
        unsigned int* dp = pairs + (size_t)b * CAPB + gb;
        const unsigned int* sp = stage + bs[b];
        for (int o = ln; o < c; o += 64) dp[o] = sp[o];
    }
    if (blockIdx.x == 0 && t < (e & 3)) {   // tail (e not multiple of 4)
        int i = (e & ~3) + t;
        int d = dst[i];
        int b = d >> 7;
        int r = atomicAdd(&bucket_cursor[b], 1);
        if (r < CAPB)
            pairs[(size_t)b * CAPB + r] =
                ((unsigned int)src[i] << 7) | (unsigned int)(d & 127);
    }
}

// ---------------- pass 2: per-bucket LDS sort -> rowinfo + src_sorted ------
__global__ void __launch_bounds__(512)
k_bucket_sort(const unsigned int* __restrict__ pairs,
              const int* __restrict__ bucket_cursor,
              int2* __restrict__ rowinfo, int* __restrict__ src_sorted,
              int n) {
    __shared__ int cnt[NPB];
    __shared__ int cur[NPB];
    __shared__ int total;
    __shared__ unsigned int lp[CAPB];
    __shared__ int op[CAPB];
    int b = blockIdx.x;
    int t = threadIdx.x;
    int bbase = b * CAPB;
    int m = bucket_cursor[b];               // relative cursor = exact count
    if (m > CAPB) m = CAPB;
    if (t < NPB) cnt[t] = 0;
    __syncthreads();
    for (int cb = 0; cb < m; cb += 4096) {
        unsigned int pv[8];
#pragma unroll
        for (int u = 0; u < 8; u++) {
            int i = cb + u * 512 + t;
            pv[u] = (i < m) ? pairs[bbase + i] : PAD_SENTINEL;
        }
#pragma unroll
        for (int u = 0; u < 8; u++) {
            int i = cb + u * 512 + t;
            if (i < m) lp[i] = pv[u];
            if (pv[u] != PAD_SENTINEL) atomicAdd(&cnt[pv[u] & 127], 1);
        }
    }
    __syncthreads();
    if (t < 64) {                       // wave 0 only: shfl scan over 128 bins
        int c0 = cnt[2 * t];
        int c1 = cnt[2 * t + 1];
        int sum = c0 + c1;
        int run = sum;
#pragma unroll
        for (int off = 1; off < 64; off <<= 1) {
            int v = __shfl_up(run, off, 64);
            if (t >= off) run += v;
        }
        int ex = run - sum;             // exclusive
        cur[2 * t] = ex;
        cur[2 * t + 1] = ex + c0;
        int node = b * NPB + 2 * t;
        if (node < n) rowinfo[node] = make_int2(bbase + ex, c0);
        if (node + 1 < n) rowinfo[node + 1] = make_int2(bbase + ex + c0, c1);
        if (t == 63) total = run;       // dense entry count
    }
    __syncthreads();
    for (int cb = 0; cb < m; cb += 4096) {
        unsigned int pv[8];
        int of[8];
#pragma unroll
        for (int u = 0; u < 8; u++) {
            int i = cb + u * 512 + t;
            pv[u] = (i < m) ? lp[i] : PAD_SENTINEL;
        }
#pragma unroll
        for (int u = 0; u < 8; u++)
            if (pv[u] != PAD_SENTINEL) of[u] = atomicAdd(&cur[pv[u] & 127], 1);
#pragma unroll
        for (int u = 0; u < 8; u++)
            if (pv[u] != PAD_SENTINEL) op[of[u]] = (int)(pv[u] >> 7);
    }
    __syncthreads();
    int nt4 = (total + 3) >> 2;
    int4* dst4 = (int4*)(src_sorted + bbase);
    const int4* src4 = (const int4*)op;
    for (int i = t; i < nt4; i += 512) dst4[i] = src4[i];
}

// ---------------- per-layer dense transform ----------------
template <int H>
__global__ void k_transform(const float* __restrict__ in, const float* __restrict__ W,
                            const float* __restrict__ att_s, const float* __restrict__ att_d,
                            __half* __restrict__ h16, float* __restrict__ a_s,
                            float* __restrict__ a_d, int n) {
    constexpr int C = 32 / H;
    __shared__ float Wl[32][33];
    __shared__ float xs[8][32];
    int t = threadIdx.x;
    for (int i = t; i < 1024; i += 256) Wl[i >> 5][i & 31] = W[i];
    int nl = t >> 5, o = t & 31;
    int node = blockIdx.x * 8 + nl;
    xs[nl][o] = (node < n) ? in[node * 32 + o] : 0.f;
    __syncthreads();
    float acc = 0.f;
#pragma unroll
    for (int k = 0; k < 32; k++) acc = fmaf(xs[nl][k], Wl[o][k], acc);
    if (node < n) {
        h16[node * 32 + o] = __float2half_rn(acc);
        float vs = acc * att_s[o];
        float vd = acc * att_d[o];
#pragma unroll
        for (int m = C / 2; m >= 1; m >>= 1) {
            vs += __shfl_xor(vs, m, 64);
            vd += __shfl_xor(vd, m, 64);
        }
        if ((o % C) == 0) {
            int hh = o / C;
            a_s[node * H + hh] = vs;
            a_d[node * H + hh] = vd;
        }
    }
}

// ---------------- per-layer fused edge softmax + aggregation ----------------
// TWO NODES PER WAVE: half-wave (32 lanes) per node. 8 nodes per 256-block.
// Pass A: half-wave lane-per-edge (stride 32), stash (s,ex) per head in LDS
//         zero-padded to mult of 16; denominator partials.
// Pass B: 2 slots x 16 channel-lanes per node; 16 edges/node/iteration via
//         4 ds_read_b128 + 8 half2 gathers in flight + 16 fma_mix.
// Denominator: 5-level half-wave butterfly after pass B; acc: 1 level.
// EPI: 0 = bias only (layer3), 1 = layer1 epilogue, 2 = elu+clip (layer2).
template <int H, int EPI>
__global__ void k_edge(const int2* __restrict__ rowinfo, const int* __restrict__ src_sorted,
                       const __half* __restrict__ h16,
                       const float* __restrict__ a_s, const float* __restrict__ a_d,
                       const float* __restrict__ bias, const float* __restrict__ ea,
                       float* __restrict__ out, int n, float slope) {
    constexpr int CAP = 128;                  // entries per node per head
    constexpr int RSTR = 2 * CAP + 16;        // region stride in ints (+64B pad)
    __shared__ int lds_raw[8][H][RSTR];
    int nw = threadIdx.x >> 5;                // node slot 0..7
    int hl = threadIdx.x & 31;                // half-wave lane
    int node = blockIdx.x * 8 + nw;
    if (node >= n) return;
    int2 bi = rowinfo[node];
    int beg = bi.x, deg = bi.y;
    int padB = (deg + 15) & ~15;

    float ad[H];
#pragma unroll
    for (int hh = 0; hh < H; hh++) ad[hh] = a_d[node * H + hh];

    // ---- pass A: stash (s, ex) per head + denominator partials ----
    float ds[H];
#pragma unroll
    for (int hh = 0; hh < H; hh++) ds[hh] = 0.f;
    bool fast = (padB <= CAP);
    if (fast) {
        for (int idx = hl; idx < padB; idx += 32) {
            if (idx < deg) {
                int s = src_sorted[beg + idx];
                if (H == 2) {
                    float2 as2 = *(const float2*)((const char*)a_s + (unsigned)(s << 3));
                    float l0 = as2.x + ad[0]; l0 = fmaxf(l0, l0 * slope);
                    float l1 = as2.y + ad[1]; l1 = fmaxf(l1, l1 * slope);
                    float e0 = __expf(l0), e1 = __expf(l1);
                    ds[0] += e0; ds[1] += e1;
                    ((int2*)lds_raw[nw][0])[idx] = make_int2(s, __float_as_int(e0));
                    ((int2*)lds_raw[nw][H - 1])[idx] = make_int2(s, __float_as_int(e1));
                } else {
                    float l0 = a_s[s] + ad[0]; l0 = fmaxf(l0, l0 * slope);
                    float e0 = __expf(l0);
                    ds[0] += e0;
                    ((int2*)lds_raw[nw][0])[idx] = make_int2(s, __float_as_int(e0));
                }
            } else {
#pragma unroll
                for (int hh = 0; hh < H; hh++)
                    ((int2*)lds_raw[nw][hh])[idx] = make_int2(0, 0);
            }
        }
    } else {
        for (int idx = hl; idx < deg; idx += 32) {
            int s = src_sorted[beg + idx];
            if (H == 2) {
                float2 as2 = *(const float2*)((const char*)a_s + (unsigned)(s << 3));
                float l0 = as2.x + ad[0]; l0 = fmaxf(l0, l0 * slope);
                float l1 = as2.y + ad[1]; l1 = fmaxf(l1, l1 * slope);
                ds[0] += __expf(l0); ds[1] += __expf(l1);
            } else {
                float l0 = a_s[s] + ad[0]; l0 = fmaxf(l0, l0 * slope);
                ds[0] += __expf(l0);
            }
        }
    }

    // ---- pass B: 2 slots x 16 lanes per node; 16 edges/node/iteration ----
    int e2 = hl >> 4;          // slot 0/1
    int l16 = hl & 15;         // channel pair 0..15
    int hd = (H == 2) ? (l16 >> 3) : 0;
    int co = l16 << 2;
    float adh = ad[hd];
    float acc0 = 0.f, acc1 = 0.f;
    const char* hbase = (const char*)h16;
    const int* lb = &lds_raw[nw][hd][e2 * 4];   // entry offset 2*e2

    if (fast) {
        // slot e2 covers entries base + {0,1,4,5,8,9,12,13} + 2*e2
        for (int base = 0; base < padB; base += 16) {
            int4 qa = *(const int4*)(lb + base * 2);
            int4 qb = *(const int4*)(lb + base * 2 + 8);
            int4 qc = *(const int4*)(lb + base * 2 + 16);
            int4 qd = *(const int4*)(lb + base * 2 + 24);
            __half2 h0 = *(const __half2*)(hbase + (unsigned)((qa.x << 6) + co));
            __half2 h1 = *(const __half2*)(hbase + (unsigned)((qa.z << 6) + co));
            __half2 h2 = *(const __half2*)(hbase + (unsigned)((qb.x << 6) + co));
            __half2 h3 = *(const __half2*)(hbase + (unsigned)((qb.z << 6) + co));
            __half2 h4 = *(const __half2*)(hbase + (unsigned)((qc.x << 6) + co));
            __half2 h5 = *(const __half2*)(hbase + (unsigned)((qc.z << 6) + co));
            __half2 h6 = *(const __half2*)(hbase + (unsigned)((qd.x << 6) + co));
            __half2 h7 = *(const __half2*)(hbase + (unsigned)((qd.z << 6) + co));
            float xa0 = __int_as_float(qa.y), xa1 = __int_as_float(qa.w);
            float xb0 = __int_as_float(qb.y), xb1 = __int_as_float(qb.w);
            float xc0 = __int_as_float(qc.y), xc1 = __int_as_float(qc.w);
            float xd0 = __int_as_float(qd.y), xd1 = __int_as_float(qd.w);
            acc0 = fmaf(xa0, __half2float(__low2half(h0)), acc0);
            acc1 = fmaf(xa0, __half2float(__high2half(h0)), acc1);
            acc0 = fmaf(xa1, __half2float(__low2half(h1)), acc0);
            acc1 = fmaf(xa1, __half2float(__high2half(h1)), acc1);
            acc0 = fmaf(xb0, __half2float(__low2half(h2)), acc0);
            acc1 = fmaf(xb0, __half2float(__high2half(h2)), acc1);
            acc0 = fmaf(xb1, __half2float(__low2half(h3)), acc0);
            acc1 = fmaf(xb1, __half2float(__high2half(h3)), acc1);
            acc0 = fmaf(xc0, __half2float(__low2half(h4)), acc0);
            acc1 = fmaf(xc0, __half2float(__high2half(h4)), acc1);
            acc0 = fmaf(xc1, __half2float(__low2half(h5)), acc0);
            acc1 = fmaf(xc1, __half2float(__high2half(h5)), acc1);
            acc0 = fmaf(xd0, __half2float(__low2half(h6)), acc0);
            acc1 = fmaf(xd0, __half2float(__high2half(h6)), acc1);
            acc0 = fmaf(xd1, __half2float(__low2half(h7)), acc0);
            acc1 = fmaf(xd1, __half2float(__high2half(h7)), acc1);
        }
    } else {
        for (int base = 0; base < deg; base += 16) {
#pragma unroll
            for (int u = 0; u < 8; u++) {
                int idx = base + u * 2 + e2;
                int s = 0;
                float ex = 0.f;
                if (idx < deg) {
                    s = src_sorted[beg + idx];
                    float l = a_s[s * H + hd] + adh;
                    l = fmaxf(l, l * slope);
                    ex = __expf(l);
                }
                __half2 hv = *(const __half2*)(hbase + (unsigned)((s << 6) + co));
                acc0 = fmaf(ex, __half2float(__low2half(hv)), acc0);
                acc1 = fmaf(ex, __half2float(__high2half(hv)), acc1);
            }
        }
    }

    // ---- denominator reduction (5-level half-wave butterfly, deferred) ----
#pragma unroll
    for (int hh = 0; hh < H; hh++) {
        float v = ds[hh];
#pragma unroll
        for (int m = 16; m >= 1; m >>= 1) v += __shfl_xor(v, m, 64);
        ds[hh] = 1.f / (v + 1e-16f);
    }

    // ---- reduce accs across the 2 slots (1 level) ----
    acc0 += __shfl_xor(acc0, 16, 64);
    acc1 += __shfl_xor(acc1, 16, 64);

    if (l16 == hl) {           // hl < 16: slot-0 lanes hold the result
        float invd = ds[hd];
        float2 bv = *(const float2*)(bias + l16 * 2);
        float v0 = fmaf(acc0, invd, bv.x);
        float v1 = fmaf(acc1, invd, bv.y);
        if (EPI == 1) {
            float s0 = tanhf(ea[0]);
            if (s0 < 0.1f) s0 = 1.0f;
            s0 *= 1.05f;
            v0 *= s0; v1 *= s0;
            v0 = (v0 > 0.f) ? v0 : expm1f(v0);
            v1 = (v1 > 0.f) ? v1 : expm1f(v1);
            v0 = fminf(3.f, fmaxf(-3.f, v0));
            v1 = fminf(3.f, fmaxf(-3.f, v1));
        } else if (EPI == 2) {
            v0 = (v0 > 0.f) ? v0 : expm1f(v0);
            v1 = (v1 > 0.f) ? v1 : expm1f(v1);
            v0 = fminf(3.f, fmaxf(-3.f, v0));
            v1 = fminf(3.f, fmaxf(-3.f, v1));
        }
        *(float2*)(out + (size_t)node * 32 + l16 * 2) = make_float2(v0, v1);
    }
}

// ---------------------------------------------------------------------------
extern "C" void kernel_launch(void* const* d_in, const int* in_sizes, int n_in,
                              void* d_out, int out_size, void* d_ws, size_t ws_size,
                              hipStream_t stream) {
    const float* x   = (const float*)d_in[0];
    const int*   ei  = (const int*)d_in[1];
    const float* W1  = (const float*)d_in[2];
    const float* as1 = (const float*)d_in[3];
    const float* ad1 = (const float*)d_in[4];
    const float* b1  = (const float*)d_in[5];
    const float* ea1 = (const float*)d_in[6];
    const float* W2  = (const float*)d_in[7];
    const float* as2 = (const float*)d_in[8];
    const float* ad2 = (const float*)d_in[9];
    const float* b2  = (const float*)d_in[10];
    const float* W3  = (const float*)d_in[11];
    const float* as3 = (const float*)d_in[12];
    const float* ad3 = (const float*)d_in[13];
    const float* b3  = (const float*)d_in[14];
    float* out = (float*)d_out;

    const int n = in_sizes[0] / 32;   // 100000
    const int e = in_sizes[1] / 2;    // 3200000
    const int* src = ei;
    const int* dst = ei + e;
    const int nb = (n + NPB - 1) / NPB;   // 782 buckets

    char* w = (char*)d_ws;
    auto alloc = [&](size_t bytes) -> void* {
        void* p = (void*)w;
        w += (bytes + 255) & ~(size_t)255;
        return p;
    };
    __half* h16     = (__half*)alloc((size_t)n * 32 * 2);
    float* a_s      = (float*)alloc((size_t)n * 2 * 4);
    float* a_d      = (float*)alloc((size_t)n * 2 * 4);
    float* bufA     = (float*)alloc((size_t)n * 32 * 4);
    float* bufB     = (float*)alloc((size_t)n * 32 * 4);
    int2* rowinfo   = (int2*)alloc((size_t)n * 8);
    int* bucket_cur = (int*)alloc((size_t)(nb + 1) * 4);
    int* src_sorted = (int*)alloc((size_t)nb * CAPB * 4);
    unsigned int* pairs = (unsigned int*)bufA;   // aliased; consumed pre-layer1

    // ---- build CSR by dst (LDS-staged bucket binning, exact counts) ----
    hipMemsetAsync(bucket_cur, 0, (size_t)nb * 4, stream);   // relative cursors
    int e4 = e >> 2;
    k_bin<<<(e4 + 2047) / 2048, 1024, 0, stream>>>(src, dst, bucket_cur, pairs, e, nb);
    k_bucket_sort<<<nb, 512, 0, stream>>>(pairs, bucket_cur, rowinfo, src_sorted, n);

    const int tgrid = (n + 7) / 8;
    const int egrid = (n + 7) / 8;

    // ---- layer 1 ----
    k_transform<2><<<tgrid, 256, 0, stream>>>(x, W1, as1, ad1, h16, a_s, a_d, n);
    k_edge<2, 1><<<egrid, 256, 0, stream>>>(rowinfo, src_sorted, h16, a_s, a_d, b1, ea1, bufA, n, 0.01f);

    // ---- layer 2 ----
    k_transform<2><<<tgrid, 256, 0, stream>>>(bufA, W2, as2, ad2, h16, a_s, a_d, n);
    k_edge<2, 2><<<egrid, 256, 0, stream>>>(rowinfo, src_sorted, h16, a_s, a_d, b2, nullptr, bufB, n, 0.2f);

    // ---- layer 3 ----
    k_transform<1><<<tgrid, 256, 0, stream>>>(bufB, W3, as3, ad3, h16, a_s, a_d, n);
    k_edge<1, 0><<<egrid, 256, 0, stream>>>(rowinfo, src_sorted, h16, a_s, a_d, b3, nullptr, out, n, 0.2f);
}